// Round 13
// baseline (69.902 us; speedup 1.0000x reference)
//
#include <hip/hip_runtime.h>

#define B_ 8
#define P_ 65536
#define G_ 32
#define C_ 2
#define K_ 5
#define T1_ 0.35f
#define T2_ 0.5f
#define ALPHA_ 0.25f
#define BETA_ 0.11f
#define V0_ 0.1f
#define V1_ 0.2f

#define NBLK_ 256                 // kA / kB-part blocks per image (1 anchor/thread)
#define CH_ 8                     // top-5 chunks per (b,g)
#define CHP_ (P_ / CH_)           // 8192 anchors per chunk

// ws layout (plain-store scratch; every word written each call before any read):
//   [0)      float  best_score[B_*P_]        2 MB
//   +2MB     int    best_idx[B_*P_]          2 MB
//   +4MB     double fl_n_p[2048]; sl_n_p[2048]          32 KB
//   +..      float  cv5[256*8*5]; int ci5[256*8*5]      80 KB
//   +..      int    histA[256][256]; histC[256][256]    512 KB   ([b*32+g][blk])

// ---------------- numerics helpers (contract off => deterministic across call sites) ----
struct DecBox { float x1, y1, x2, y2, area; };

__device__ __forceinline__ DecBox decode_box(float4 pr, float4 lc) {
#pragma clang fp contract(off)
    DecBox d;
    float dcx = pr.x + lc.x * V0_ * pr.z;
    float dcy = pr.y + lc.y * V0_ * pr.w;
    float dw = pr.z * expf(lc.z * V1_);
    float dh = pr.w * expf(lc.w * V1_);
    d.x1 = dcx - dw * 0.5f; d.y1 = dcy - dh * 0.5f;
    d.x2 = dcx + dw * 0.5f; d.y2 = dcy + dh * 0.5f;
    d.area = (d.x2 - d.x1) * (d.y2 - d.y1);
    return d;
}

__device__ __forceinline__ float iou_dec(DecBox d, float aa,
                                         float tx1, float ty1, float tx2, float ty2) {
#pragma clang fp contract(off)
    float lx = fmaxf(tx1, d.x1), ly = fmaxf(ty1, d.y1);
    float rx = fminf(tx2, d.x2), ry = fminf(ty2, d.y2);
    float w = fmaxf(rx - lx, 0.f), hh = fmaxf(ry - ly, 0.f);
    float inter = w * hh;
    return inter / (aa + d.area - inter);
}

__device__ __forceinline__ float focal_f(float t, float x, float fiou) {
    float ce = fmaxf(x, 0.f) - x * t + log1pf(expf(-fabsf(x)));
    float a = (t * ALPHA_ + (1.f - t) * (1.f - ALPHA_)) * fiou;
    float pt = (t == 1.0f) ? x : 1.f - x;
    float om = 1.f - pt;
    return a * om * om * ce;  // GAMMA = 2
}

__device__ __forceinline__ float sml1(float p, float t) {
    float x = fabsf(p - t);
    return (x >= BETA_) ? (x - 0.5f * BETA_) : (0.5f * x * x / BETA_);
}

// top-5 by (value desc, index asc) — the stable-argsort order
__device__ __forceinline__ void top5_insert(float v, int i, float lv[5], int li[5]) {
    if ((v > lv[4]) || (v == lv[4] && i < li[4])) {
        lv[4] = v; li[4] = i;
#pragma unroll
        for (int k = 4; k > 0; --k) {
            bool sw = (lv[k] > lv[k - 1]) || (lv[k] == lv[k - 1] && li[k] < li[k - 1]);
            if (sw) {
                float tv = lv[k]; lv[k] = lv[k - 1]; lv[k - 1] = tv;
                int ti = li[k]; li[k] = li[k - 1]; li[k - 1] = ti;
            }
        }
    }
}

// ---------------- kA: best match per anchor (1/thread, 2048 blocks); row-major hist ----
__global__ __launch_bounds__(256) void kA(const float* __restrict__ priors,
                                          const float* __restrict__ targets,
                                          float* __restrict__ best_score,
                                          int* __restrict__ best_idx,
                                          int* __restrict__ histA) {
    int tid = threadIdx.x, blk = blockIdx.x, b = blockIdx.y;
    __shared__ float tr[G_ * 5];
    __shared__ float gA[G_];
    __shared__ int hist[G_];
    if (tid < G_ * 5) tr[tid] = targets[b * G_ * 5 + tid];
    if (tid < G_) hist[tid] = 0;
    __syncthreads();
    if (tid < G_)
        gA[tid] = (tr[tid * 5 + 2] - tr[tid * 5 + 0]) * (tr[tid * 5 + 3] - tr[tid * 5 + 1]);
    __syncthreads();
    int p = blk * 256 + tid;
    float4 pr = ((const float4*)priors)[p];
    float px1 = pr.x - pr.z * 0.5f, py1 = pr.y - pr.w * 0.5f;
    float px2 = pr.x + pr.z * 0.5f, py2 = pr.y + pr.w * 0.5f;
    float parea = (px2 - px1) * (py2 - py1);
    float best = -INFINITY;
    int bix = 0;
    for (int g = 0; g < G_; ++g) {
        float lx = fmaxf(tr[g * 5 + 0], px1), ly = fmaxf(tr[g * 5 + 1], py1);
        float rx = fminf(tr[g * 5 + 2], px2), ry = fminf(tr[g * 5 + 3], py2);
        float w = fmaxf(rx - lx, 0.f), hh = fmaxf(ry - ly, 0.f);
        float inter = w * hh;
        float v = inter / (gA[g] + parea - inter);
        if (v > best) { best = v; bix = g; }  // first-max == jnp.argmax
    }
    best_score[b * P_ + p] = best;
    best_idx[b * P_ + p] = bix;
    if (best > T1_) atomicAdd(&hist[bix], 1);  // LDS atomic only
    __syncthreads();
    if (tid < G_) histA[(b * G_ + tid) * NBLK_ + blk] = hist[tid];  // row-major [bg][blk]
}

// ---------------- kBD: heterogeneous. x<256: kB part. x>=256: kD chunk top-5 -----------
__global__ __launch_bounds__(256) void kBD(
    const float* __restrict__ loc, const float* __restrict__ conf,
    const float* __restrict__ priors, const float* __restrict__ targets,
    const float* __restrict__ best_score, const int* __restrict__ best_idx,
    const int* __restrict__ histA,
    int* __restrict__ histC,
    double* __restrict__ fl_n_p, double* __restrict__ sl_n_p,
    float* __restrict__ cv5, int* __restrict__ ci5) {
    int tid = threadIdx.x, b = blockIdx.y;
    __shared__ union USm {
        struct {
            float tr[G_ * 5]; float gA[G_];
            int outf[G_]; int hist[G_]; double wred[8];
        } Bp;
        struct { float sv[256 * 5]; int si[256 * 5]; int wsum[4]; } Dp;
    } u;

    if (blockIdx.x < NBLK_) {
        // ================= kB part (1 anchor/thread) =================
        int blk = blockIdx.x;
        if (tid < G_ * 5) u.Bp.tr[tid] = targets[b * G_ * 5 + tid];
        if (tid < G_) u.Bp.hist[tid] = 0;
        {   // match_cnt: 8 threads per g; thread reads 32 CONTIGUOUS ints of row (b,g)
            int g = tid >> 3, l8 = tid & 7;
            const int* row = histA + (b * G_ + g) * NBLK_ + l8 * 32;
            int s = 0;
#pragma unroll
            for (int j = 0; j < 32; ++j) s += row[j];
            s += __shfl_down(s, 4, 8);
            s += __shfl_down(s, 2, 8);
            s += __shfl_down(s, 1, 8);
            if (l8 == 0) u.Bp.outf[g] = (s < K_) ? 1 : 0;
        }
        __syncthreads();
        if (tid < G_)
            u.Bp.gA[tid] = (u.Bp.tr[tid * 5 + 2] - u.Bp.tr[tid * 5 + 0]) *
                           (u.Bp.tr[tid * 5 + 3] - u.Bp.tr[tid * 5 + 1]);
        __syncthreads();

        int p = blk * 256 + tid;
        float4 pr = ((const float4*)priors)[p];
        float4 lc = ((const float4*)loc)[(size_t)b * P_ + p];
        float bs = best_score[b * P_ + p];
        int bi = best_idx[b * P_ + p];
        DecBox d = decode_box(pr, lc);
        bool n_pos = bs > T1_;
        float cmax = -INFINITY, mbest = -INFINITY;
        int mg = 0;
        for (int g = 0; g < G_; ++g) {
            float v = iou_dec(d, u.Bp.gA[g], u.Bp.tr[g * 5], u.Bp.tr[g * 5 + 1],
                              u.Bp.tr[g * 5 + 2], u.Bp.tr[g * 5 + 3]);
            cmax = fmaxf(cmax, v);
            bool kill = u.Bp.outf[g] && (bi == g) && n_pos;
            float v2 = kill ? 0.f : v;
            float m = u.Bp.outf[g] ? v2 : -1.f;
            if (m > mbest) { mbest = m; mg = g; }  // first-max
        }
        if (mbest > T2_) atomicAdd(&u.Bp.hist[mg], 1);  // LDS atomic only
        bool ignore = (cmax > T2_) && (bs < T1_);
        bool neg = !(n_pos || ignore);
        double fl = 0.0, sl = 0.0;
        int lab = (int)u.Bp.tr[bi * 5 + 4];
        float2 cf = ((const float2*)conf)[(size_t)b * P_ + p];
        float cfs[2] = {cf.x, cf.y};
#pragma unroll
        for (int c = 0; c < C_; ++c) {
            if (n_pos) fl += (double)focal_f((c == lab) ? 1.f : 0.f, cfs[c], 1.f);
            else if (neg) fl += (double)focal_f(0.f, cfs[c], 1.f);
        }
        if (n_pos) {
            float tx1 = u.Bp.tr[bi * 5], ty1 = u.Bp.tr[bi * 5 + 1];
            float tx2 = u.Bp.tr[bi * 5 + 2], ty2 = u.Bp.tr[bi * 5 + 3];
            float e0 = ((tx1 + tx2) * 0.5f - pr.x) / (V0_ * pr.z);
            float e1 = ((ty1 + ty2) * 0.5f - pr.y) / (V0_ * pr.w);
            float e2 = logf((tx2 - tx1) / pr.z) / V1_;
            float e3 = logf((ty2 - ty1) / pr.w) / V1_;
            sl = (double)sml1(lc.x, e0) + (double)sml1(lc.y, e1) +
                 (double)sml1(lc.z, e2) + (double)sml1(lc.w, e3);
        }
        int lane = tid & 63, w = tid >> 6;
        for (int off = 32; off > 0; off >>= 1) {
            fl += __shfl_down(fl, off, 64);
            sl += __shfl_down(sl, off, 64);
        }
        if (lane == 0) { u.Bp.wred[w] = fl; u.Bp.wred[4 + w] = sl; }
        __syncthreads();  // wred + hist final
        if (tid == 0)
            fl_n_p[b * NBLK_ + blk] = u.Bp.wred[0] + u.Bp.wred[1] + u.Bp.wred[2] + u.Bp.wred[3];
        if (tid == 1)
            sl_n_p[b * NBLK_ + blk] = u.Bp.wred[4] + u.Bp.wred[5] + u.Bp.wred[6] + u.Bp.wred[7];
        if (tid < G_) histC[(b * G_ + tid) * NBLK_ + blk] = u.Bp.hist[tid];
    } else {
        // ================= kD part: chunked top-5, gated on mc<K (rare) =================
        int t2 = blockIdx.x - NBLK_;
        int tg = t2 >> 3, tch = t2 & (CH_ - 1), tb = b;
        {   // mc = row sum, fully coalesced: 1 int per thread
            int v = histA[(tb * G_ + tg) * NBLK_ + tid];
            for (int off = 32; off > 0; off >>= 1) v += __shfl_down(v, off, 64);
            if ((tid & 63) == 0) u.Dp.wsum[tid >> 6] = v;
        }
        __syncthreads();
        int mc = u.Dp.wsum[0] + u.Dp.wsum[1] + u.Dp.wsum[2] + u.Dp.wsum[3];
        if (mc >= K_) return;  // uniform per block; almost always exits here

        const float* tgp = targets + (tb * G_ + tg) * 5;
        float tx1 = tgp[0], ty1 = tgp[1], tx2 = tgp[2], ty2 = tgp[3];
        float aa = (tx2 - tx1) * (ty2 - ty1);
        float lv[5];
        int li[5];
#pragma unroll
        for (int k = 0; k < 5; ++k) { lv[k] = -INFINITY; li[k] = 0x7fffffff; }
        int base = tch * CHP_;
        for (int it = 0; it < CHP_ / 256; ++it) {
            int p = base + it * 256 + tid;
            int pbi = best_idx[tb * P_ + p];
            float pbs = best_score[tb * P_ + p];
            float v2;
            if (pbi == tg && pbs > T1_) v2 = 0.f;  // kill (outface true: mc<K)
            else {
                float4 pr = ((const float4*)priors)[p];
                float4 lc = ((const float4*)loc)[(size_t)tb * P_ + p];
                v2 = iou_dec(decode_box(pr, lc), aa, tx1, ty1, tx2, ty2);
            }
            top5_insert(v2, p, lv, li);
        }
#pragma unroll
        for (int k = 0; k < 5; ++k) { u.Dp.sv[tid * 5 + k] = lv[k]; u.Dp.si[tid * 5 + k] = li[k]; }
        __syncthreads();
        for (int str = 128; str > 0; str >>= 1) {
            if (tid < str) {
                int a = 0, c = 0;
                float ov[5];
                int oi[5];
#pragma unroll
                for (int k = 0; k < 5; ++k) {
                    float va = u.Dp.sv[tid * 5 + a], vb = u.Dp.sv[(tid + str) * 5 + c];
                    int ia = u.Dp.si[tid * 5 + a], ib = u.Dp.si[(tid + str) * 5 + c];
                    bool ta = (va > vb) || (va == vb && ia < ib);
                    ov[k] = ta ? va : vb;
                    oi[k] = ta ? ia : ib;
                    if (ta) a++; else c++;
                }
#pragma unroll
                for (int k = 0; k < 5; ++k) { u.Dp.sv[tid * 5 + k] = ov[k]; u.Dp.si[tid * 5 + k] = oi[k]; }
            }
            __syncthreads();
        }
        if (tid == 0) {
#pragma unroll
            for (int k = 0; k < 5; ++k) {
                cv5[((tb * G_ + tg) * CH_ + tch) * 5 + k] = u.Dp.sv[k];
                ci5[((tb * G_ + tg) * CH_ + tch) * 5 + k] = u.Dp.si[k];
            }
        }
    }
}

// ---------------- kTail: int4-stream row sums, merge chunks, overrides, finalize --------
__global__ __launch_bounds__(256) void kTail(
    const float* __restrict__ loc, const float* __restrict__ conf,
    const float* __restrict__ priors, const float* __restrict__ targets,
    const int* __restrict__ histA, const int* __restrict__ histC,
    const double* __restrict__ fl_n_p, const double* __restrict__ sl_n_p,
    const float* __restrict__ cv5, const int* __restrict__ ci5,
    float* __restrict__ out) {
    int t = threadIdx.x, b = t >> 5, g = t & 31;
    __shared__ int selp[256][5];
    __shared__ int nS[256];
    __shared__ double aFlc[B_], aSlc[B_], aFln[B_], aSln[B_];
    __shared__ int aNp[B_], aCs[B_], aNpc[B_];

    // mc/cm: each thread streams its own 256-int row as 64 int4 loads
    int mc = 0, cm = 0;
    {
        const int4* rA = (const int4*)(histA + t * NBLK_);
        const int4* rC = (const int4*)(histC + t * NBLK_);
#pragma unroll 8
        for (int j = 0; j < NBLK_ / 4; ++j) {
            int4 a = rA[j], c = rC[j];
            mc += a.x + a.y + a.z + a.w;
            cm += c.x + c.y + c.z + c.w;
        }
    }
    int n = (mc < K_) ? min(cm, K_ - mc) : 0;
    nS[t] = n;
    float mv[5];
    int mi[5];
#pragma unroll
    for (int k = 0; k < 5; ++k) { mv[k] = -INFINITY; mi[k] = 0x7fffffff; }
    if (n > 0) {
        for (int ch = 0; ch < CH_; ++ch)
#pragma unroll
            for (int k = 0; k < 5; ++k)
                top5_insert(cv5[(t * CH_ + ch) * 5 + k], ci5[(t * CH_ + ch) * 5 + k], mv, mi);
    }
#pragma unroll
    for (int k = 0; k < 5; ++k) selp[t][k] = (k < n) ? mi[k] : -1;
    __syncthreads();

    // override resolution (ascending g: later g wins) + compensation losses
    double flc = 0.0, slc = 0.0;
    int alive = 0;
    float tg0 = targets[t * 5 + 0], tg1 = targets[t * 5 + 1];
    float tg2 = targets[t * 5 + 2], tg3 = targets[t * 5 + 3];
    float labf = targets[t * 5 + 4];
    int labi = (int)labf;
    for (int k = 0; k < n; ++k) {
        int p = mi[k];
        bool dead = false;
        for (int g2 = g + 1; g2 < G_; ++g2) {
            int q = b * G_ + g2;
            int n2 = nS[q];
            for (int k2 = 0; k2 < n2; ++k2)
                if (selp[q][k2] == p) dead = true;
        }
        if (!dead) {
            alive++;
            float4 pr = ((const float4*)priors)[p];
            float4 lc = ((const float4*)loc)[(size_t)b * P_ + p];
            float e0 = ((tg0 + tg2) * 0.5f - pr.x) / (V0_ * pr.z);
            float e1 = ((tg1 + tg3) * 0.5f - pr.y) / (V0_ * pr.w);
            float e2 = logf((tg2 - tg0) / pr.z) / V1_;
            float e3 = logf((tg3 - tg1) / pr.w) / V1_;
            slc += (double)sml1(lc.x, e0) + (double)sml1(lc.y, e1) +
                   (double)sml1(lc.z, e2) + (double)sml1(lc.w, e3);
            float2 cf = ((const float2*)conf)[(size_t)b * P_ + p];
            float cfs[2] = {cf.x, cf.y};
#pragma unroll
            for (int c = 0; c < C_; ++c) {
                float tt = (c == labi) ? labf : 0.f;  // labels[g] * one_hot
                flc += (double)focal_f(tt, cfs[c], mv[k]);
            }
        }
    }

    // per-b reductions within 32-thread subgroups (256 partial slots per image)
    int rmc = mc, rn = n, ra = alive;
    double rf = flc, rs = slc;
    double pf = 0.0, ps = 0.0;
#pragma unroll
    for (int j = 0; j < 8; ++j) {
        pf += fl_n_p[b * NBLK_ + g * 8 + j];
        ps += sl_n_p[b * NBLK_ + g * 8 + j];
    }
    for (int off = 16; off > 0; off >>= 1) {
        rmc += __shfl_down(rmc, off, 32);
        rn += __shfl_down(rn, off, 32);
        ra += __shfl_down(ra, off, 32);
        rf += __shfl_down(rf, off, 32);
        rs += __shfl_down(rs, off, 32);
        pf += __shfl_down(pf, off, 32);
        ps += __shfl_down(ps, off, 32);
    }
    if (g == 0) {
        aNp[b] = rmc; aCs[b] = rn; aNpc[b] = ra;
        aFlc[b] = rf; aSlc[b] = rs; aFln[b] = pf; aSln[b] = ps;
    }
    __syncthreads();
    if (t == 0) {
        double sll = 0.0, scl = 0.0;
        for (int b2 = 0; b2 < B_; ++b2) {
            double l_loc = 0.0, l_cls = 0.0;
            int npos = aNp[b2];
            if (npos > 0) {
                l_cls += aFln[b2] / (double)npos;
                l_loc += aSln[b2] / (double)npos;
            }
            int csum = aCs[b2];
            if (csum > 0) {
                int npc = (aNpc[b2] > 1) ? aNpc[b2] : 1;
                l_loc += aSlc[b2] / (double)npc;
                l_cls += aFlc[b2] / (double)csum;
            }
            sll += l_loc;
            scl += l_cls;
        }
        out[0] = (float)(sll / B_);
        out[1] = (float)(scl / B_);
    }
}

extern "C" void kernel_launch(void* const* d_in, const int* in_sizes, int n_in,
                              void* d_out, int out_size, void* d_ws, size_t ws_size,
                              hipStream_t stream) {
    (void)in_sizes; (void)n_in; (void)out_size; (void)ws_size;
    const float* loc = (const float*)d_in[0];
    const float* conf = (const float*)d_in[1];
    const float* priors = (const float*)d_in[2];
    const float* targets = (const float*)d_in[3];
    float* out = (float*)d_out;
    char* ws = (char*)d_ws;

    float* best_score = (float*)ws;                               // 2 MB
    int* best_idx = (int*)(ws + (size_t)2 * 1024 * 1024);         // 2 MB
    double* fl_n_p = (double*)(ws + (size_t)4 * 1024 * 1024);     // 2048 doubles
    double* sl_n_p = fl_n_p + B_ * NBLK_;                         // 2048 doubles
    float* cv5 = (float*)(sl_n_p + B_ * NBLK_);                   // 10240 floats
    int* ci5 = (int*)(cv5 + B_ * G_ * CH_ * 5);                   // 10240 ints
    int* histA = ci5 + B_ * G_ * CH_ * 5;                         // 64K ints
    int* histC = histA + B_ * G_ * NBLK_;                         // 64K ints

    kA<<<dim3(NBLK_, B_), 256, 0, stream>>>(priors, targets, best_score, best_idx, histA);
    kBD<<<dim3(NBLK_ + G_ * CH_, B_), 256, 0, stream>>>(loc, conf, priors, targets,
                                                        best_score, best_idx, histA,
                                                        histC, fl_n_p, sl_n_p, cv5, ci5);
    kTail<<<1, 256, 0, stream>>>(loc, conf, priors, targets, histA, histC,
                                 fl_n_p, sl_n_p, cv5, ci5, out);
}

// Round 14
// 52.234 us; speedup vs baseline: 1.3383x; 1.3383x over previous
//
#include <hip/hip_runtime.h>

#define B_ 8
#define P_ 65536
#define G_ 32
#define C_ 2
#define K_ 5
#define T1_ 0.35f
#define T2_ 0.5f
#define ALPHA_ 0.25f
#define BETA_ 0.11f
#define V0_ 0.1f
#define V1_ 0.2f

#define NBLK_ 256   // blocks per image in kAB (1 anchor/thread)

// ws layout (plain-store scratch; every word written each call before any read):
//   [0)      float  best_score[B_*P_]        2 MB
//   +2MB     int    best_idx[B_*P_]          2 MB
//   +4MB     double fl_n_p[2048]; sl_n_p[2048]   32 KB
//   +..      int    histA[256][256]   ([blk][b*32+g], write+read coalesced)  256 KB

// ---------------- numerics helpers (contract off => deterministic across call sites) ----
struct DecBox { float x1, y1, x2, y2, area; };

__device__ __forceinline__ DecBox decode_box(float4 pr, float4 lc) {
#pragma clang fp contract(off)
    DecBox d;
    float dcx = pr.x + lc.x * V0_ * pr.z;
    float dcy = pr.y + lc.y * V0_ * pr.w;
    float dw = pr.z * expf(lc.z * V1_);
    float dh = pr.w * expf(lc.w * V1_);
    d.x1 = dcx - dw * 0.5f; d.y1 = dcy - dh * 0.5f;
    d.x2 = dcx + dw * 0.5f; d.y2 = dcy + dh * 0.5f;
    d.area = (d.x2 - d.x1) * (d.y2 - d.y1);
    return d;
}

__device__ __forceinline__ float iou_dec(DecBox d, float aa,
                                         float tx1, float ty1, float tx2, float ty2) {
#pragma clang fp contract(off)
    float lx = fmaxf(tx1, d.x1), ly = fmaxf(ty1, d.y1);
    float rx = fminf(tx2, d.x2), ry = fminf(ty2, d.y2);
    float w = fmaxf(rx - lx, 0.f), hh = fmaxf(ry - ly, 0.f);
    float inter = w * hh;
    return inter / (aa + d.area - inter);
}

__device__ __forceinline__ float focal_f(float t, float x, float fiou) {
    float ce = fmaxf(x, 0.f) - x * t + log1pf(expf(-fabsf(x)));
    float a = (t * ALPHA_ + (1.f - t) * (1.f - ALPHA_)) * fiou;
    float pt = (t == 1.0f) ? x : 1.f - x;
    float om = 1.f - pt;
    return a * om * om * ce;  // GAMMA = 2
}

__device__ __forceinline__ float sml1(float p, float t) {
    float x = fabsf(p - t);
    return (x >= BETA_) ? (x - 0.5f * BETA_) : (0.5f * x * x / BETA_);
}

// top-5 by (value desc, index asc) — the stable-argsort order
__device__ __forceinline__ void top5_insert(float v, int i, float lv[5], int li[5]) {
    if ((v > lv[4]) || (v == lv[4] && i < li[4])) {
        lv[4] = v; li[4] = i;
#pragma unroll
        for (int k = 4; k > 0; --k) {
            bool sw = (lv[k] > lv[k - 1]) || (lv[k] == lv[k - 1] && li[k] < li[k - 1]);
            if (sw) {
                float tv = lv[k]; lv[k] = lv[k - 1]; lv[k - 1] = tv;
                int ti = li[k]; li[k] = li[k - 1]; li[k - 1] = ti;
            }
        }
    }
}

// ================= kAB: anchor-local phase A + ALL normal losses in one pass ===========
// Normal losses need only best_score (A) and UNMASKED cmax — no match_cnt dependency.
__global__ __launch_bounds__(256) void kAB(
    const float* __restrict__ loc, const float* __restrict__ conf,
    const float* __restrict__ priors, const float* __restrict__ targets,
    float* __restrict__ best_score, int* __restrict__ best_idx,
    int* __restrict__ histA,
    double* __restrict__ fl_n_p, double* __restrict__ sl_n_p) {
    int tid = threadIdx.x, blk = blockIdx.x, b = blockIdx.y;
    __shared__ float tr[G_ * 5];
    __shared__ float gA[G_];
    __shared__ int hist[G_];
    __shared__ double wred[8];
    if (tid < G_ * 5) tr[tid] = targets[b * G_ * 5 + tid];
    if (tid < G_) hist[tid] = 0;
    __syncthreads();
    if (tid < G_)
        gA[tid] = (tr[tid * 5 + 2] - tr[tid * 5 + 0]) * (tr[tid * 5 + 3] - tr[tid * 5 + 1]);
    __syncthreads();

    int p = blk * 256 + tid;
    float4 pr = ((const float4*)priors)[p];
    float4 lc = ((const float4*)loc)[(size_t)b * P_ + p];

    // ---- phase A: prior<->gt IoU, first-max ----
    float px1 = pr.x - pr.z * 0.5f, py1 = pr.y - pr.w * 0.5f;
    float px2 = pr.x + pr.z * 0.5f, py2 = pr.y + pr.w * 0.5f;
    float parea = (px2 - px1) * (py2 - py1);
    float best = -INFINITY;
    int bix = 0;
    for (int g = 0; g < G_; ++g) {
        float lx = fmaxf(tr[g * 5 + 0], px1), ly = fmaxf(tr[g * 5 + 1], py1);
        float rx = fminf(tr[g * 5 + 2], px2), ry = fminf(tr[g * 5 + 3], py2);
        float w = fmaxf(rx - lx, 0.f), hh = fmaxf(ry - ly, 0.f);
        float inter = w * hh;
        float v = inter / (gA[g] + parea - inter);
        if (v > best) { best = v; bix = g; }  // first-max == jnp.argmax
    }
    best_score[b * P_ + p] = best;
    best_idx[b * P_ + p] = bix;
    if (best > T1_) atomicAdd(&hist[bix], 1);  // LDS atomic only

    // ---- phase B: decoded IoU max (unmasked), normal focal + smoothL1 ----
    DecBox d = decode_box(pr, lc);
    float cmax = -INFINITY;
    for (int g = 0; g < G_; ++g)
        cmax = fmaxf(cmax, iou_dec(d, gA[g], tr[g * 5], tr[g * 5 + 1],
                                   tr[g * 5 + 2], tr[g * 5 + 3]));
    bool n_pos = best > T1_;
    bool ignore = (cmax > T2_) && (best < T1_);
    bool neg = !(n_pos || ignore);
    double fl = 0.0, sl = 0.0;
    int lab = (int)tr[bix * 5 + 4];
    float2 cf = ((const float2*)conf)[(size_t)b * P_ + p];
    float cfs[2] = {cf.x, cf.y};
#pragma unroll
    for (int c = 0; c < C_; ++c) {
        if (n_pos) fl += (double)focal_f((c == lab) ? 1.f : 0.f, cfs[c], 1.f);
        else if (neg) fl += (double)focal_f(0.f, cfs[c], 1.f);
    }
    if (n_pos) {
        float tx1 = tr[bix * 5], ty1 = tr[bix * 5 + 1];
        float tx2 = tr[bix * 5 + 2], ty2 = tr[bix * 5 + 3];
        float e0 = ((tx1 + tx2) * 0.5f - pr.x) / (V0_ * pr.z);
        float e1 = ((ty1 + ty2) * 0.5f - pr.y) / (V0_ * pr.w);
        float e2 = logf((tx2 - tx1) / pr.z) / V1_;
        float e3 = logf((ty2 - ty1) / pr.w) / V1_;
        sl = (double)sml1(lc.x, e0) + (double)sml1(lc.y, e1) +
             (double)sml1(lc.z, e2) + (double)sml1(lc.w, e3);
    }
    int lane = tid & 63, w = tid >> 6;
    for (int off = 32; off > 0; off >>= 1) {
        fl += __shfl_down(fl, off, 64);
        sl += __shfl_down(sl, off, 64);
    }
    if (lane == 0) { wred[w] = fl; wred[4 + w] = sl; }
    __syncthreads();  // wred + hist final
    if (tid == 0)
        fl_n_p[b * NBLK_ + blk] = wred[0] + wred[1] + wred[2] + wred[3];
    if (tid == 1)
        sl_n_p[b * NBLK_ + blk] = wred[4] + wred[5] + wred[6] + wred[7];
    if (tid < G_) histA[blk * 256 + b * G_ + tid] = hist[tid];  // 32 consecutive ints
}

// ================= kTail2: everything outf-dependent, one block =========================
// Common case (no row with mc<K): pure reduction, ~µs. Rare case: in-block c_match scan
// + per-row top-5 passes, only for deficient rows.
__global__ __launch_bounds__(256) void kTail2(
    const float* __restrict__ loc, const float* __restrict__ conf,
    const float* __restrict__ priors, const float* __restrict__ targets,
    const float* __restrict__ best_score, const int* __restrict__ best_idx,
    const int* __restrict__ histA,
    const double* __restrict__ fl_n_p, const double* __restrict__ sl_n_p,
    float* __restrict__ out) {
    int t = threadIdx.x, b = t >> 5, g = t & 31;
    __shared__ int mcS[256], nS[256];
    __shared__ int selp[256][5];
    __shared__ float mvS[256][5];
    __shared__ int miS[256][5];
    __shared__ int outCnt[B_];
    __shared__ float tr2[G_ * 5], gA2[G_];
    __shared__ int outf2[G_], cmH[G_];
    __shared__ float sv[256 * 5];
    __shared__ int si[256 * 5];
    __shared__ double aFlc[B_], aSlc[B_], aFln[B_], aSln[B_];
    __shared__ int aNp[B_], aCs[B_], aNpc[B_];

    // ---- mc: column sums of histA, fully coalesced (iter blk: threads read 256 consec) --
    int mc = 0;
    for (int blk = 0; blk < NBLK_; ++blk) mc += histA[blk * 256 + t];
    mcS[t] = mc;
    nS[t] = 0;
    if (t < B_) outCnt[t] = 0;
    __syncthreads();
    if (mc < K_) atomicAdd(&outCnt[b], 1);  // LDS atomic
    __syncthreads();

    // ---- rare path: per image with deficient rows, c_match scan + top-5 passes ---------
    for (int b2 = 0; b2 < B_; ++b2) {
        if (outCnt[b2] == 0) continue;  // uniform
        if (t < G_ * 5) tr2[t] = targets[b2 * G_ * 5 + t];
        if (t < G_) { outf2[t] = (mcS[b2 * G_ + t] < K_) ? 1 : 0; cmH[t] = 0; }
        __syncthreads();
        if (t < G_)
            gA2[t] = (tr2[t * 5 + 2] - tr2[t * 5 + 0]) * (tr2[t * 5 + 3] - tr2[t * 5 + 1]);
        __syncthreads();
        // c_match: masked first-argmax per anchor over outf rows
        for (int it = 0; it < P_ / 256; ++it) {
            int p = it * 256 + t;
            float bs = best_score[b2 * P_ + p];
            int bi = best_idx[b2 * P_ + p];
            float4 pr = ((const float4*)priors)[p];
            float4 lc = ((const float4*)loc)[(size_t)b2 * P_ + p];
            DecBox d = decode_box(pr, lc);
            float mbest = -1.f;
            int mg = 0;
            for (int g2 = 0; g2 < G_; ++g2) {
                if (!outf2[g2]) continue;
                float v2 = (bi == g2 && bs > T1_) ? 0.f
                           : iou_dec(d, gA2[g2], tr2[g2 * 5], tr2[g2 * 5 + 1],
                                     tr2[g2 * 5 + 2], tr2[g2 * 5 + 3]);
                if (v2 > mbest) { mbest = v2; mg = g2; }  // first-max
            }
            if (mbest > T2_) atomicAdd(&cmH[mg], 1);
        }
        __syncthreads();
        if (t < G_) {
            int mcr = mcS[b2 * G_ + t];
            nS[b2 * G_ + t] = (mcr < K_) ? min(cmH[t], K_ - mcr) : 0;
        }
        __syncthreads();
        // top-5 pass per row needing compensation
        for (int g2 = 0; g2 < G_; ++g2) {
            int row = b2 * G_ + g2;
            if (nS[row] <= 0) continue;  // uniform
            float tx1 = tr2[g2 * 5], ty1 = tr2[g2 * 5 + 1];
            float tx2 = tr2[g2 * 5 + 2], ty2 = tr2[g2 * 5 + 3];
            float aa = gA2[g2];
            float lv[5];
            int li[5];
#pragma unroll
            for (int k = 0; k < 5; ++k) { lv[k] = -INFINITY; li[k] = 0x7fffffff; }
            for (int it = 0; it < P_ / 256; ++it) {
                int p = it * 256 + t;
                float bs = best_score[b2 * P_ + p];
                int bi = best_idx[b2 * P_ + p];
                float v2;
                if (bi == g2 && bs > T1_) v2 = 0.f;  // kill
                else {
                    float4 pr = ((const float4*)priors)[p];
                    float4 lc = ((const float4*)loc)[(size_t)b2 * P_ + p];
                    v2 = iou_dec(decode_box(pr, lc), aa, tx1, ty1, tx2, ty2);
                }
                top5_insert(v2, p, lv, li);
            }
#pragma unroll
            for (int k = 0; k < 5; ++k) { sv[t * 5 + k] = lv[k]; si[t * 5 + k] = li[k]; }
            __syncthreads();
            for (int str = 128; str > 0; str >>= 1) {
                if (t < str) {
                    int a = 0, c = 0;
                    float ov[5];
                    int oi[5];
#pragma unroll
                    for (int k = 0; k < 5; ++k) {
                        float va = sv[t * 5 + a], vb = sv[(t + str) * 5 + c];
                        int ia = si[t * 5 + a], ib = si[(t + str) * 5 + c];
                        bool ta = (va > vb) || (va == vb && ia < ib);
                        ov[k] = ta ? va : vb;
                        oi[k] = ta ? ia : ib;
                        if (ta) a++; else c++;
                    }
#pragma unroll
                    for (int k = 0; k < 5; ++k) { sv[t * 5 + k] = ov[k]; si[t * 5 + k] = oi[k]; }
                }
                __syncthreads();
            }
            if (t < 5) { mvS[row][t] = sv[t]; miS[row][t] = si[t]; }
            __syncthreads();
        }
    }

    // ---- selection arrays ----
    int n = nS[t];
#pragma unroll
    for (int k = 0; k < 5; ++k) selp[t][k] = (k < n) ? miS[t][k] : -1;
    __syncthreads();

    // ---- override resolution (ascending g: later g wins) + compensation losses --------
    double flc = 0.0, slc = 0.0;
    int alive = 0;
    float tg0 = targets[t * 5 + 0], tg1 = targets[t * 5 + 1];
    float tg2 = targets[t * 5 + 2], tg3 = targets[t * 5 + 3];
    float labf = targets[t * 5 + 4];
    int labi = (int)labf;
    for (int k = 0; k < n; ++k) {
        int p = miS[t][k];
        bool dead = false;
        for (int g2 = g + 1; g2 < G_; ++g2) {
            int q = b * G_ + g2;
            int n2 = nS[q];
            for (int k2 = 0; k2 < n2; ++k2)
                if (selp[q][k2] == p) dead = true;
        }
        if (!dead) {
            alive++;
            float4 pr = ((const float4*)priors)[p];
            float4 lc = ((const float4*)loc)[(size_t)b * P_ + p];
            float e0 = ((tg0 + tg2) * 0.5f - pr.x) / (V0_ * pr.z);
            float e1 = ((tg1 + tg3) * 0.5f - pr.y) / (V0_ * pr.w);
            float e2 = logf((tg2 - tg0) / pr.z) / V1_;
            float e3 = logf((tg3 - tg1) / pr.w) / V1_;
            slc += (double)sml1(lc.x, e0) + (double)sml1(lc.y, e1) +
                   (double)sml1(lc.z, e2) + (double)sml1(lc.w, e3);
            float2 cf = ((const float2*)conf)[(size_t)b * P_ + p];
            float cfs[2] = {cf.x, cf.y};
#pragma unroll
            for (int c = 0; c < C_; ++c) {
                float tt = (c == labi) ? labf : 0.f;  // labels[g] * one_hot
                flc += (double)focal_f(tt, cfs[c], mvS[t][k]);
            }
        }
    }

    // ---- per-b reductions within 32-thread subgroups -----------------------------------
    int rmc = mcS[t], rn = n, ra = alive;
    double rf = flc, rs = slc;
    double pf = 0.0, ps = 0.0;
#pragma unroll
    for (int j = 0; j < 8; ++j) {
        pf += fl_n_p[b * NBLK_ + g * 8 + j];
        ps += sl_n_p[b * NBLK_ + g * 8 + j];
    }
    for (int off = 16; off > 0; off >>= 1) {
        rmc += __shfl_down(rmc, off, 32);
        rn += __shfl_down(rn, off, 32);
        ra += __shfl_down(ra, off, 32);
        rf += __shfl_down(rf, off, 32);
        rs += __shfl_down(rs, off, 32);
        pf += __shfl_down(pf, off, 32);
        ps += __shfl_down(ps, off, 32);
    }
    if (g == 0) {
        aNp[b] = rmc; aCs[b] = rn; aNpc[b] = ra;
        aFlc[b] = rf; aSlc[b] = rs; aFln[b] = pf; aSln[b] = ps;
    }
    __syncthreads();
    if (t == 0) {
        double sll = 0.0, scl = 0.0;
        for (int b2 = 0; b2 < B_; ++b2) {
            double l_loc = 0.0, l_cls = 0.0;
            int npos = aNp[b2];
            if (npos > 0) {
                l_cls += aFln[b2] / (double)npos;
                l_loc += aSln[b2] / (double)npos;
            }
            int csum = aCs[b2];
            if (csum > 0) {
                int npc = (aNpc[b2] > 1) ? aNpc[b2] : 1;
                l_loc += aSlc[b2] / (double)npc;
                l_cls += aFlc[b2] / (double)csum;
            }
            sll += l_loc;
            scl += l_cls;
        }
        out[0] = (float)(sll / B_);
        out[1] = (float)(scl / B_);
    }
}

extern "C" void kernel_launch(void* const* d_in, const int* in_sizes, int n_in,
                              void* d_out, int out_size, void* d_ws, size_t ws_size,
                              hipStream_t stream) {
    (void)in_sizes; (void)n_in; (void)out_size; (void)ws_size;
    const float* loc = (const float*)d_in[0];
    const float* conf = (const float*)d_in[1];
    const float* priors = (const float*)d_in[2];
    const float* targets = (const float*)d_in[3];
    float* out = (float*)d_out;
    char* ws = (char*)d_ws;

    float* best_score = (float*)ws;                               // 2 MB
    int* best_idx = (int*)(ws + (size_t)2 * 1024 * 1024);         // 2 MB
    double* fl_n_p = (double*)(ws + (size_t)4 * 1024 * 1024);     // 2048 doubles
    double* sl_n_p = fl_n_p + B_ * NBLK_;                         // 2048 doubles
    int* histA = (int*)(sl_n_p + B_ * NBLK_);                     // 64K ints

    kAB<<<dim3(NBLK_, B_), 256, 0, stream>>>(loc, conf, priors, targets,
                                             best_score, best_idx, histA,
                                             fl_n_p, sl_n_p);
    kTail2<<<1, 256, 0, stream>>>(loc, conf, priors, targets, best_score, best_idx,
                                  histA, fl_n_p, sl_n_p, out);
}

// Round 15
// 35.722 us; speedup vs baseline: 1.9568x; 1.4622x over previous
//
#include <hip/hip_runtime.h>

#define B_ 8
#define P_ 65536
#define G_ 32
#define C_ 2
#define K_ 5
#define T1_ 0.35f
#define T2_ 0.5f
#define ALPHA_ 0.25f
#define BETA_ 0.11f
#define V0_ 0.1f
#define V1_ 0.2f

#define NBLK_ 256   // blocks per image in kAB (1 anchor/thread)

// ws layout (plain-store scratch; every word written each call before any read):
//   [0)      float  best_score[B_*P_]        2 MB
//   +2MB     int    best_idx[B_*P_]          2 MB
//   +4MB     double fl_n_p[2048]; sl_n_p[2048]   32 KB
//   +..      int    histA[256][256]   ([blk][b*32+g], write+read coalesced)  256 KB

// ---------------- numerics helpers (contract off => deterministic across call sites) ----
struct DecBox { float x1, y1, x2, y2, area; };

__device__ __forceinline__ DecBox decode_box(float4 pr, float4 lc) {
#pragma clang fp contract(off)
    DecBox d;
    float dcx = pr.x + lc.x * V0_ * pr.z;
    float dcy = pr.y + lc.y * V0_ * pr.w;
    float dw = pr.z * expf(lc.z * V1_);
    float dh = pr.w * expf(lc.w * V1_);
    d.x1 = dcx - dw * 0.5f; d.y1 = dcy - dh * 0.5f;
    d.x2 = dcx + dw * 0.5f; d.y2 = dcy + dh * 0.5f;
    d.area = (d.x2 - d.x1) * (d.y2 - d.y1);
    return d;
}

__device__ __forceinline__ float iou_dec(DecBox d, float aa,
                                         float tx1, float ty1, float tx2, float ty2) {
#pragma clang fp contract(off)
    float lx = fmaxf(tx1, d.x1), ly = fmaxf(ty1, d.y1);
    float rx = fminf(tx2, d.x2), ry = fminf(ty2, d.y2);
    float w = fmaxf(rx - lx, 0.f), hh = fmaxf(ry - ly, 0.f);
    float inter = w * hh;
    return inter / (aa + d.area - inter);
}

__device__ __forceinline__ float focal_f(float t, float x, float fiou) {
    float ce = fmaxf(x, 0.f) - x * t + log1pf(expf(-fabsf(x)));
    float a = (t * ALPHA_ + (1.f - t) * (1.f - ALPHA_)) * fiou;
    float pt = (t == 1.0f) ? x : 1.f - x;
    float om = 1.f - pt;
    return a * om * om * ce;  // GAMMA = 2
}

__device__ __forceinline__ float sml1(float p, float t) {
    float x = fabsf(p - t);
    return (x >= BETA_) ? (x - 0.5f * BETA_) : (0.5f * x * x / BETA_);
}

// top-5 by (value desc, index asc) — the stable-argsort order
__device__ __forceinline__ void top5_insert(float v, int i, float lv[5], int li[5]) {
    if ((v > lv[4]) || (v == lv[4] && i < li[4])) {
        lv[4] = v; li[4] = i;
#pragma unroll
        for (int k = 4; k > 0; --k) {
            bool sw = (lv[k] > lv[k - 1]) || (lv[k] == lv[k - 1] && li[k] < li[k - 1]);
            if (sw) {
                float tv = lv[k]; lv[k] = lv[k - 1]; lv[k - 1] = tv;
                int ti = li[k]; li[k] = li[k - 1]; li[k - 1] = ti;
            }
        }
    }
}

// ================= kAB: fused single g-loop, division-free compares ====================
// Phase A argmax tracked as a fraction (iB,uB): update iff inter*uB > iB*uni (unions>0).
// Ignore flag: exists g with decoded-IoU > T2  <=>  inter2 > T2*uni2. No divisions in loop;
// one division at the end reproduces the reference's winning quotient exactly.
__global__ __launch_bounds__(256) void kAB(
    const float* __restrict__ loc, const float* __restrict__ conf,
    const float* __restrict__ priors, const float* __restrict__ targets,
    float* __restrict__ best_score, int* __restrict__ best_idx,
    int* __restrict__ histA,
    double* __restrict__ fl_n_p, double* __restrict__ sl_n_p) {
    int tid = threadIdx.x, blk = blockIdx.x, b = blockIdx.y;
    __shared__ float tr[G_ * 5];
    __shared__ float4 trB[G_];
    __shared__ float gA[G_];
    __shared__ int hist[G_];
    __shared__ double wred[8];
    if (tid < G_ * 5) tr[tid] = targets[b * G_ * 5 + tid];
    if (tid < G_) hist[tid] = 0;
    __syncthreads();
    if (tid < G_) {
        float t0 = tr[tid * 5], t1 = tr[tid * 5 + 1];
        float t2 = tr[tid * 5 + 2], t3 = tr[tid * 5 + 3];
        trB[tid] = make_float4(t0, t1, t2, t3);
        gA[tid] = (t2 - t0) * (t3 - t1);
    }
    __syncthreads();

    int p = blk * 256 + tid;
    float4 pr = ((const float4*)priors)[p];
    float4 lc = ((const float4*)loc)[(size_t)b * P_ + p];
    float px1 = pr.x - pr.z * 0.5f, py1 = pr.y - pr.w * 0.5f;
    float px2 = pr.x + pr.z * 0.5f, py2 = pr.y + pr.w * 0.5f;
    float parea = (px2 - px1) * (py2 - py1);
    DecBox d = decode_box(pr, lc);

    float iB = -1.f, uB = 1.f;   // best prior-IoU as fraction; g0 always wins 1st compare
    int bix = 0;
    bool ign = false;
    for (int g = 0; g < G_; ++g) {
        float4 tb = trB[g];      // single ds_read_b128 broadcast
        float ga = gA[g];
        // prior-box IoU fraction + argmax (first-max preserved: strict >)
        float lx = fmaxf(tb.x, px1), ly = fmaxf(tb.y, py1);
        float rx = fminf(tb.z, px2), ry = fminf(tb.w, py2);
        float w = fmaxf(rx - lx, 0.f), hh = fmaxf(ry - ly, 0.f);
        float inter = w * hh;
        float uni = ga + parea - inter;
        if (inter * uB > iB * uni) { iB = inter; uB = uni; bix = g; }
        // decoded-box IoU > T2 flag (unmasked cmax usage only)
        float lx2 = fmaxf(tb.x, d.x1), ly2 = fmaxf(tb.y, d.y1);
        float rx2 = fminf(tb.z, d.x2), ry2 = fminf(tb.w, d.y2);
        float w2 = fmaxf(rx2 - lx2, 0.f), h2 = fmaxf(ry2 - ly2, 0.f);
        float inter2 = w2 * h2;
        float uni2 = ga + d.area - inter2;
        ign |= (inter2 > T2_ * uni2);
    }
    float best = iB / uB;        // winning g's quotient, IEEE-identical to reference
    best_score[b * P_ + p] = best;
    best_idx[b * P_ + p] = bix;
    if (best > T1_) atomicAdd(&hist[bix], 1);  // LDS atomic only

    bool n_pos = best > T1_;
    bool ignore = ign && (best < T1_);
    double fl = 0.0, sl = 0.0;
    float2 cf = ((const float2*)conf)[(size_t)b * P_ + p];
    if (!ignore) {               // single focal path: t = one-hot iff n_pos
        int lab = (int)tr[bix * 5 + 4];
        float cfs[2] = {cf.x, cf.y};
#pragma unroll
        for (int c = 0; c < C_; ++c) {
            float t = (n_pos && c == lab) ? 1.f : 0.f;
            fl += (double)focal_f(t, cfs[c], 1.f);
        }
    }
    if (n_pos) {
        float tx1 = tr[bix * 5], ty1 = tr[bix * 5 + 1];
        float tx2 = tr[bix * 5 + 2], ty2 = tr[bix * 5 + 3];
        float e0 = ((tx1 + tx2) * 0.5f - pr.x) / (V0_ * pr.z);
        float e1 = ((ty1 + ty2) * 0.5f - pr.y) / (V0_ * pr.w);
        float e2 = logf((tx2 - tx1) / pr.z) / V1_;
        float e3 = logf((ty2 - ty1) / pr.w) / V1_;
        sl = (double)sml1(lc.x, e0) + (double)sml1(lc.y, e1) +
             (double)sml1(lc.z, e2) + (double)sml1(lc.w, e3);
    }
    int lane = tid & 63, w = tid >> 6;
    for (int off = 32; off > 0; off >>= 1) {
        fl += __shfl_down(fl, off, 64);
        sl += __shfl_down(sl, off, 64);
    }
    if (lane == 0) { wred[w] = fl; wred[4 + w] = sl; }
    __syncthreads();  // wred + hist final
    if (tid == 0)
        fl_n_p[b * NBLK_ + blk] = wred[0] + wred[1] + wred[2] + wred[3];
    if (tid == 1)
        sl_n_p[b * NBLK_ + blk] = wred[4] + wred[5] + wred[6] + wred[7];
    if (tid < G_) histA[blk * 256 + b * G_ + tid] = hist[tid];  // 32 consecutive ints
}

// ================= kTail2: everything outf-dependent, one block (unchanged, R14) ========
__global__ __launch_bounds__(256) void kTail2(
    const float* __restrict__ loc, const float* __restrict__ conf,
    const float* __restrict__ priors, const float* __restrict__ targets,
    const float* __restrict__ best_score, const int* __restrict__ best_idx,
    const int* __restrict__ histA,
    const double* __restrict__ fl_n_p, const double* __restrict__ sl_n_p,
    float* __restrict__ out) {
    int t = threadIdx.x, b = t >> 5, g = t & 31;
    __shared__ int mcS[256], nS[256];
    __shared__ int selp[256][5];
    __shared__ float mvS[256][5];
    __shared__ int miS[256][5];
    __shared__ int outCnt[B_];
    __shared__ float tr2[G_ * 5], gA2[G_];
    __shared__ int outf2[G_], cmH[G_];
    __shared__ float sv[256 * 5];
    __shared__ int si[256 * 5];
    __shared__ double aFlc[B_], aSlc[B_], aFln[B_], aSln[B_];
    __shared__ int aNp[B_], aCs[B_], aNpc[B_];

    int mc = 0;
    for (int blk = 0; blk < NBLK_; ++blk) mc += histA[blk * 256 + t];
    mcS[t] = mc;
    nS[t] = 0;
    if (t < B_) outCnt[t] = 0;
    __syncthreads();
    if (mc < K_) atomicAdd(&outCnt[b], 1);  // LDS atomic
    __syncthreads();

    for (int b2 = 0; b2 < B_; ++b2) {
        if (outCnt[b2] == 0) continue;  // uniform
        if (t < G_ * 5) tr2[t] = targets[b2 * G_ * 5 + t];
        if (t < G_) { outf2[t] = (mcS[b2 * G_ + t] < K_) ? 1 : 0; cmH[t] = 0; }
        __syncthreads();
        if (t < G_)
            gA2[t] = (tr2[t * 5 + 2] - tr2[t * 5 + 0]) * (tr2[t * 5 + 3] - tr2[t * 5 + 1]);
        __syncthreads();
        for (int it = 0; it < P_ / 256; ++it) {
            int p = it * 256 + t;
            float bs = best_score[b2 * P_ + p];
            int bi = best_idx[b2 * P_ + p];
            float4 pr = ((const float4*)priors)[p];
            float4 lc = ((const float4*)loc)[(size_t)b2 * P_ + p];
            DecBox d = decode_box(pr, lc);
            float mbest = -1.f;
            int mg = 0;
            for (int g2 = 0; g2 < G_; ++g2) {
                if (!outf2[g2]) continue;
                float v2 = (bi == g2 && bs > T1_) ? 0.f
                           : iou_dec(d, gA2[g2], tr2[g2 * 5], tr2[g2 * 5 + 1],
                                     tr2[g2 * 5 + 2], tr2[g2 * 5 + 3]);
                if (v2 > mbest) { mbest = v2; mg = g2; }  // first-max
            }
            if (mbest > T2_) atomicAdd(&cmH[mg], 1);
        }
        __syncthreads();
        if (t < G_) {
            int mcr = mcS[b2 * G_ + t];
            nS[b2 * G_ + t] = (mcr < K_) ? min(cmH[t], K_ - mcr) : 0;
        }
        __syncthreads();
        for (int g2 = 0; g2 < G_; ++g2) {
            int row = b2 * G_ + g2;
            if (nS[row] <= 0) continue;  // uniform
            float tx1 = tr2[g2 * 5], ty1 = tr2[g2 * 5 + 1];
            float tx2 = tr2[g2 * 5 + 2], ty2 = tr2[g2 * 5 + 3];
            float aa = gA2[g2];
            float lv[5];
            int li[5];
#pragma unroll
            for (int k = 0; k < 5; ++k) { lv[k] = -INFINITY; li[k] = 0x7fffffff; }
            for (int it = 0; it < P_ / 256; ++it) {
                int p = it * 256 + t;
                float bs = best_score[b2 * P_ + p];
                int bi = best_idx[b2 * P_ + p];
                float v2;
                if (bi == g2 && bs > T1_) v2 = 0.f;  // kill
                else {
                    float4 pr = ((const float4*)priors)[p];
                    float4 lc = ((const float4*)loc)[(size_t)b2 * P_ + p];
                    v2 = iou_dec(decode_box(pr, lc), aa, tx1, ty1, tx2, ty2);
                }
                top5_insert(v2, p, lv, li);
            }
#pragma unroll
            for (int k = 0; k < 5; ++k) { sv[t * 5 + k] = lv[k]; si[t * 5 + k] = li[k]; }
            __syncthreads();
            for (int str = 128; str > 0; str >>= 1) {
                if (t < str) {
                    int a = 0, c = 0;
                    float ov[5];
                    int oi[5];
#pragma unroll
                    for (int k = 0; k < 5; ++k) {
                        float va = sv[t * 5 + a], vb = sv[(t + str) * 5 + c];
                        int ia = si[t * 5 + a], ib = si[(t + str) * 5 + c];
                        bool ta = (va > vb) || (va == vb && ia < ib);
                        ov[k] = ta ? va : vb;
                        oi[k] = ta ? ia : ib;
                        if (ta) a++; else c++;
                    }
#pragma unroll
                    for (int k = 0; k < 5; ++k) { sv[t * 5 + k] = ov[k]; si[t * 5 + k] = oi[k]; }
                }
                __syncthreads();
            }
            if (t < 5) { mvS[row][t] = sv[t]; miS[row][t] = si[t]; }
            __syncthreads();
        }
    }

    int n = nS[t];
#pragma unroll
    for (int k = 0; k < 5; ++k) selp[t][k] = (k < n) ? miS[t][k] : -1;
    __syncthreads();

    double flc = 0.0, slc = 0.0;
    int alive = 0;
    float tg0 = targets[t * 5 + 0], tg1 = targets[t * 5 + 1];
    float tg2 = targets[t * 5 + 2], tg3 = targets[t * 5 + 3];
    float labf = targets[t * 5 + 4];
    int labi = (int)labf;
    for (int k = 0; k < n; ++k) {
        int p = miS[t][k];
        bool dead = false;
        for (int g2 = g + 1; g2 < G_; ++g2) {
            int q = b * G_ + g2;
            int n2 = nS[q];
            for (int k2 = 0; k2 < n2; ++k2)
                if (selp[q][k2] == p) dead = true;
        }
        if (!dead) {
            alive++;
            float4 pr = ((const float4*)priors)[p];
            float4 lc = ((const float4*)loc)[(size_t)b * P_ + p];
            float e0 = ((tg0 + tg2) * 0.5f - pr.x) / (V0_ * pr.z);
            float e1 = ((tg1 + tg3) * 0.5f - pr.y) / (V0_ * pr.w);
            float e2 = logf((tg2 - tg0) / pr.z) / V1_;
            float e3 = logf((tg3 - tg1) / pr.w) / V1_;
            slc += (double)sml1(lc.x, e0) + (double)sml1(lc.y, e1) +
                   (double)sml1(lc.z, e2) + (double)sml1(lc.w, e3);
            float2 cf = ((const float2*)conf)[(size_t)b * P_ + p];
            float cfs[2] = {cf.x, cf.y};
#pragma unroll
            for (int c = 0; c < C_; ++c) {
                float tt = (c == labi) ? labf : 0.f;  // labels[g] * one_hot
                flc += (double)focal_f(tt, cfs[c], mvS[t][k]);
            }
        }
    }

    int rmc = mcS[t], rn = n, ra = alive;
    double rf = flc, rs = slc;
    double pf = 0.0, ps = 0.0;
#pragma unroll
    for (int j = 0; j < 8; ++j) {
        pf += fl_n_p[b * NBLK_ + g * 8 + j];
        ps += sl_n_p[b * NBLK_ + g * 8 + j];
    }
    for (int off = 16; off > 0; off >>= 1) {
        rmc += __shfl_down(rmc, off, 32);
        rn += __shfl_down(rn, off, 32);
        ra += __shfl_down(ra, off, 32);
        rf += __shfl_down(rf, off, 32);
        rs += __shfl_down(rs, off, 32);
        pf += __shfl_down(pf, off, 32);
        ps += __shfl_down(ps, off, 32);
    }
    if (g == 0) {
        aNp[b] = rmc; aCs[b] = rn; aNpc[b] = ra;
        aFlc[b] = rf; aSlc[b] = rs; aFln[b] = pf; aSln[b] = ps;
    }
    __syncthreads();
    if (t == 0) {
        double sll = 0.0, scl = 0.0;
        for (int b2 = 0; b2 < B_; ++b2) {
            double l_loc = 0.0, l_cls = 0.0;
            int npos = aNp[b2];
            if (npos > 0) {
                l_cls += aFln[b2] / (double)npos;
                l_loc += aSln[b2] / (double)npos;
            }
            int csum = aCs[b2];
            if (csum > 0) {
                int npc = (aNpc[b2] > 1) ? aNpc[b2] : 1;
                l_loc += aSlc[b2] / (double)npc;
                l_cls += aFlc[b2] / (double)csum;
            }
            sll += l_loc;
            scl += l_cls;
        }
        out[0] = (float)(sll / B_);
        out[1] = (float)(scl / B_);
    }
}

extern "C" void kernel_launch(void* const* d_in, const int* in_sizes, int n_in,
                              void* d_out, int out_size, void* d_ws, size_t ws_size,
                              hipStream_t stream) {
    (void)in_sizes; (void)n_in; (void)out_size; (void)ws_size;
    const float* loc = (const float*)d_in[0];
    const float* conf = (const float*)d_in[1];
    const float* priors = (const float*)d_in[2];
    const float* targets = (const float*)d_in[3];
    float* out = (float*)d_out;
    char* ws = (char*)d_ws;

    float* best_score = (float*)ws;                               // 2 MB
    int* best_idx = (int*)(ws + (size_t)2 * 1024 * 1024);         // 2 MB
    double* fl_n_p = (double*)(ws + (size_t)4 * 1024 * 1024);     // 2048 doubles
    double* sl_n_p = fl_n_p + B_ * NBLK_;                         // 2048 doubles
    int* histA = (int*)(sl_n_p + B_ * NBLK_);                     // 64K ints

    kAB<<<dim3(NBLK_, B_), 256, 0, stream>>>(loc, conf, priors, targets,
                                             best_score, best_idx, histA,
                                             fl_n_p, sl_n_p);
    kTail2<<<1, 256, 0, stream>>>(loc, conf, priors, targets, best_score, best_idx,
                                  histA, fl_n_p, sl_n_p, out);
}